// Round 17
// baseline (404.144 us; speedup 1.0000x reference)
//
#include <hip/hip_runtime.h>
#include <hip/hip_bf16.h>
#include <math.h>

constexpr int Dm = 1024;
constexpr int Hh = 16;
constexpr int Ff = 4096;
constexpr int Ss = 512;
constexpr int Bbatch = 16;
constexpr int NT = Bbatch * Ss;   // 8192 tokens
constexpr float EPSc = 1e-5f;

typedef __attribute__((ext_vector_type(8))) short bfrag;    // 8 bf16 (4 VGPR)
typedef __attribute__((ext_vector_type(4))) float f32x4;
typedef __attribute__((ext_vector_type(16))) float f32x16;  // 32x32 acc

// tanh-form GELU, one v_exp, NaN-safe at +-inf of e (1 - 2/(e+1))
static __device__ __forceinline__ float gelu_f(float v) {
    const float u = v * (0.7978845608f + 0.0356774081f * v * v);
    const float e = __expf(2.0f * u);
    const float th = 1.0f - 2.0f / (e + 1.0f);
    return 0.5f * v * (1.0f + th);
}

static __device__ __forceinline__ void gload16(const void* g, void* l) {
    __builtin_amdgcn_global_load_lds((__attribute__((address_space(1))) void*)g,
                                     (__attribute__((address_space(3))) void*)l,
                                     16, 0, 0);
}

// XOR swizzle for [rows][128B-row] LDS tiles (G4): byte ^= ((row&7)<<4)
#define SWZ(row, colb) ((row) * 128 + ((colb) ^ (((row) & 7) << 4)))

// ---------------- transpose + fp32->bf16 convert: in [R][C] -> out [C][R] ---
__global__ void __launch_bounds__(256) transpose_cvt(const float* __restrict__ in,
                                                     __hip_bfloat16* __restrict__ out,
                                                     int R, int C,
                                                     long in_zs, long out_zs) {
    __shared__ float tile[32][33];
    const float* inz = in + (size_t)blockIdx.z * in_zs;
    __hip_bfloat16* outz = out + (size_t)blockIdx.z * out_zs;
    const int c0 = blockIdx.x * 32, r0 = blockIdx.y * 32;
    const int tx = threadIdx.x & 31, ty4 = (threadIdx.x >> 5) * 4;
    #pragma unroll
    for (int i = 0; i < 4; i++)
        tile[ty4 + i][tx] = inz[(size_t)(r0 + ty4 + i) * C + c0 + tx];
    __syncthreads();
    #pragma unroll
    for (int i = 0; i < 4; i++)
        outz[(size_t)(c0 + ty4 + i) * R + r0 + tx] = __float2bfloat16(tile[tx][ty4 + i]);
}

// merged Wq/Wk/Wv transpose: z in [0,48), matrix = z/16, per-head slice z%16
__global__ void __launch_bounds__(256) qkv_transpose_cvt(const float* __restrict__ Wq,
                                                         const float* __restrict__ Wk,
                                                         const float* __restrict__ Wv,
                                                         __hip_bfloat16* __restrict__ out) {
    __shared__ float tile[32][33];
    const int zm = blockIdx.z >> 4, zi = blockIdx.z & 15;
    const float* inz = (zm == 0 ? Wq : (zm == 1 ? Wk : Wv)) + (size_t)zi * 65536;
    __hip_bfloat16* outz = out + (size_t)zm * 1048576 + (size_t)zi * 65536;
    const int c0 = blockIdx.x * 32, r0 = blockIdx.y * 32;   // R=1024, C=64
    const int tx = threadIdx.x & 31, ty4 = (threadIdx.x >> 5) * 4;
    #pragma unroll
    for (int i = 0; i < 4; i++)
        tile[ty4 + i][tx] = inz[(size_t)(r0 + ty4 + i) * 64 + c0 + tx];
    __syncthreads();
    #pragma unroll
    for (int i = 0; i < 4; i++)
        outz[(size_t)(c0 + ty4 + i) * 1024 + r0 + tx] = __float2bfloat16(tile[tx][ty4 + i]);
}

// ---------------- LayerNorm fp32 in -> bf16 out ----------------------------
__global__ void __launch_bounds__(256) ln_bf16(const float* __restrict__ x,
                                               const float* __restrict__ gamma,
                                               const float* __restrict__ beta,
                                               __hip_bfloat16* __restrict__ out) {
    const int row = blockIdx.x;
    const int tid = threadIdx.x;
    const int lane = tid & 63, w = tid >> 6;
    float4 xv = reinterpret_cast<const float4*>(x + (size_t)row * Dm)[tid];
    float s  = xv.x + xv.y + xv.z + xv.w;
    float ss = xv.x * xv.x + xv.y * xv.y + xv.z * xv.z + xv.w * xv.w;
    #pragma unroll
    for (int o = 32; o > 0; o >>= 1) {
        s  += __shfl_down(s,  o, 64);
        ss += __shfl_down(ss, o, 64);
    }
    __shared__ float red[2][4];
    if (lane == 0) { red[0][w] = s; red[1][w] = ss; }
    __syncthreads();
    float st  = red[0][0] + red[0][1] + red[0][2] + red[0][3];
    float sst = red[1][0] + red[1][1] + red[1][2] + red[1][3];
    float mean = st * (1.0f / Dm);
    float var  = sst * (1.0f / Dm) - mean * mean;
    float inv  = rsqrtf(var + EPSc);
    float4 g = reinterpret_cast<const float4*>(gamma)[tid];
    float4 b = reinterpret_cast<const float4*>(beta)[tid];
    __hip_bfloat16 t[4] __attribute__((aligned(8)));
    t[0] = __float2bfloat16((xv.x - mean) * inv * g.x + b.x);
    t[1] = __float2bfloat16((xv.y - mean) * inv * g.y + b.y);
    t[2] = __float2bfloat16((xv.z - mean) * inv * g.z + b.z);
    t[3] = __float2bfloat16((xv.w - mean) * inv * g.w + b.w);
    *reinterpret_cast<ushort4*>(out + (size_t)row * Dm + tid * 4) =
        *reinterpret_cast<ushort4*>(t);
}

// ---------------- bf16 MFMA GEMM: R13 structure, 32x32x16 fragments --------
// C = A[M,K] x Bt[N,K]^T. 128x128 tile, BK=64, 4 waves (2x2), 64 KiB dbuf,
// distance-2 prefetch (vmcnt(8), never 0 mid-loop), 8x8 super-tile order.
// Fragment shape swapped 16x16x32 -> 32x32x16: per wave per K-tile 16 MFMA
// (8.07cyc, m119 2495TF ceiling) instead of 32 (4.85cyc, 2176TF) — same
// ds_read count, same acc VGPRs. C-layout (m74/m101, R7-verified):
// col=lane&31, row=(r&3)+8*(r>>2)+4*(lane>>5).
// EPI 0: bf16 C                EPI 1: f32 C = acc + bias + res
// EPI 2: bf16 C = gelu(acc+b)  EPI 3: f32 C += acc + bias
template<int EPI>
__global__ void __launch_bounds__(256) gemm_db(const __hip_bfloat16* __restrict__ A, int lda,
                                               const __hip_bfloat16* __restrict__ Bt, int ldb,
                                               const float* __restrict__ bias,
                                               const float* __restrict__ res,
                                               void* __restrict__ Cout, int ldc,
                                               int nbx, int K) {
    __shared__ __hip_bfloat16 As[2][128 * 64];
    __shared__ __hip_bfloat16 Bs[2][128 * 64];
    const int tid = threadIdx.x, l = tid & 63, w = tid >> 6;
    const int lr32 = l & 31, lh = l >> 5;
    const int nwg = gridDim.x;
    const int sbid = (blockIdx.x & 7) * (nwg >> 3) + (blockIdx.x >> 3);
    // 8x8 super-tile mapping (per-XCD L2 working set ~4MB)
    const int st = sbid >> 6, wi = sbid & 63;
    const int nsx = nbx >> 3;
    const int bx = (st % nsx) * 8 + (wi & 7);
    const int by = (st / nsx) * 8 + (wi >> 3);
    const int m0 = by * 128, n0 = bx * 128;
    const int wr = w >> 1, wc = w & 1;
    const int srow = l >> 3;
    const int scol = ((l & 7) ^ srow) * 8;
    const int NK = K >> 6;

    // uniform bases (advance 64 elems/tile) + loop-invariant per-lane offsets
    const __hip_bfloat16* ubA = A  + (size_t)m0 * lda;
    const __hip_bfloat16* ubB = Bt + (size_t)n0 * ldb;
    int offA[4], offB[4];
    #pragma unroll
    for (int j = 0; j < 4; j++) {
        offA[j] = (w * 32 + j * 8 + srow) * lda + scol;
        offB[j] = (w * 32 + j * 8 + srow) * ldb + scol;
    }
    auto STAGE = [&](int bsel) {              // 8 gload16/thread, then advance
        #pragma unroll
        for (int j = 0; j < 4; j++) {
            const int rb = w * 32 + j * 8;
            gload16(ubA + offA[j], &As[bsel][rb * 64]);
            gload16(ubB + offB[j], &Bs[bsel][rb * 64]);
        }
        ubA += 64; ubB += 64;
    };

    f32x16 acc[2][2] = {};
    STAGE(0);
    STAGE(1);
    for (int t = 0; t < NK; t++) {
        const int cur = t & 1;
        if (t + 1 < NK) asm volatile("s_waitcnt vmcnt(8)" ::: "memory");
        else            asm volatile("s_waitcnt vmcnt(0)" ::: "memory");
        __builtin_amdgcn_s_barrier();
        const char* Ab = (const char*)&As[cur][0];
        const char* Bb = (const char*)&Bs[cur][0];
        #pragma unroll
        for (int ks = 0; ks < 4; ks++) {       // K=16 steps within BK=64
            const int g = ks * 2 + lh;         // 16B granule index 0..7
            bfrag a[2], b[2];
            #pragma unroll
            for (int mi = 0; mi < 2; mi++) {
                const int row = wr * 64 + mi * 32 + lr32;
                a[mi] = *(const bfrag*)(Ab + row * 128 + ((g ^ (row & 7)) << 4));
            }
            #pragma unroll
            for (int ni = 0; ni < 2; ni++) {
                const int row = wc * 64 + ni * 32 + lr32;
                b[ni] = *(const bfrag*)(Bb + row * 128 + ((g ^ (row & 7)) << 4));
            }
            #pragma unroll
            for (int mi = 0; mi < 2; mi++)
                #pragma unroll
                for (int ni = 0; ni < 2; ni++)
                    acc[mi][ni] = __builtin_amdgcn_mfma_f32_32x32x16_bf16(
                        a[mi], b[ni], acc[mi][ni], 0, 0, 0);
        }
        __builtin_amdgcn_s_barrier();         // all reads of buf[cur] done
        if (t + 2 < NK) STAGE(cur);           // tile t+2 -> just-freed buffer
    }
    // epilogue: 32x32 C layout (col=lane&31, row=(r&3)+8*(r>>2)+4*lh)
    #pragma unroll
    for (int mi = 0; mi < 2; mi++) {
        #pragma unroll
        for (int ni = 0; ni < 2; ni++) {
            const int col = n0 + wc * 64 + ni * 32 + lr32;
            const float bv = (EPI != 0) ? bias[col] : 0.0f;
            #pragma unroll
            for (int r = 0; r < 16; r++) {
                const int row = m0 + wr * 64 + mi * 32 + (r & 3) + 8 * (r >> 2) + 4 * lh;
                const size_t off = (size_t)row * ldc + col;
                const float v = acc[mi][ni][r];
                if (EPI == 0) {
                    ((__hip_bfloat16*)Cout)[off] = __float2bfloat16(v);
                } else if (EPI == 1) {
                    ((float*)Cout)[off] = v + bv + res[off];
                } else if (EPI == 2) {
                    ((__hip_bfloat16*)Cout)[off] = __float2bfloat16(gelu_f(v + bv));
                } else {
                    ((float*)Cout)[off] = ((float*)Cout)[off] + v + bv;
                }
            }
        }
    }
}

// ---------------- Flash attention: K/V double-buffered, counted vmcnt ------
// (R10-R16 proven kernel, unchanged.)
__global__ void __launch_bounds__(256) attn_mfma(const __hip_bfloat16* __restrict__ QKV,
                                                 __hip_bfloat16* __restrict__ Oc) {
    constexpr int LDQ = 3072;
    __shared__ __hip_bfloat16 Qs[64 * 64];
    __shared__ __hip_bfloat16 Ks[2][64 * 64];
    __shared__ __hip_bfloat16 Vts[2][64 * 64];   // V^T [feat][key]
    __shared__ __hip_bfloat16 Ps[4][16 * 64];    // per-wave P
    const int tid = threadIdx.x, l = tid & 63, w = tid >> 6;
    const int lr = l & 15, lg = l >> 4;
    const int qt = 7 - (blockIdx.x & 7);         // LPT: heavy tiles first
    const int h  = (blockIdx.x >> 3) & 15;
    const int b  = blockIdx.x >> 7;

    const __hip_bfloat16* Qg = QKV + (size_t)(b * Ss + qt * 64) * LDQ + h * 64;
    const __hip_bfloat16* Kg = QKV + (size_t)(b * Ss) * LDQ + 1024 + h * 64;
    const __hip_bfloat16* Vg = QKV + (size_t)(b * Ss) * LDQ + 2048 + h * 64;

    const int r8 = l >> 3;
    const int scol = 8 * ((l & 7) ^ r8);         // pre-swizzled source col

    const int vkey0 = tid >> 3, vf0 = (tid & 7) * 8;
    const int vkey1 = (tid + 256) >> 3, vf1 = vf0;

    uint4 vr[2];
    auto VLOAD = [&](int kt) {
        vr[0] = *reinterpret_cast<const uint4*>(Vg + (size_t)(kt * 64 + vkey0) * LDQ + vf0);
        vr[1] = *reinterpret_cast<const uint4*>(Vg + (size_t)(kt * 64 + vkey1) * LDQ + vf1);
    };
    auto VWRITE = [&](int bsel) {
        unsigned short* vt = reinterpret_cast<unsigned short*>(Vts[bsel]);
        #pragma unroll
        for (int j = 0; j < 2; j++) {
            const int key = j ? vkey1 : vkey0, f0 = j ? vf1 : vf0;
            const unsigned int rw[4] = {vr[j].x, vr[j].y, vr[j].z, vr[j].w};
            #pragma unroll
            for (int e2 = 0; e2 < 8; e2++) {
                const int feat = f0 + e2;
                const int ad = feat * 128 + ((key * 2) ^ ((feat & 7) << 4));
                vt[ad >> 1] = (unsigned short)(rw[e2 >> 1] >> ((e2 & 1) * 16));
            }
        }
    };
    auto KSTAGE = [&](int kt, int bsel) {
        #pragma unroll
        for (int j = 0; j < 2; j++) {
            const int slot = w * 2 + j;
            gload16(Kg + (size_t)(kt * 64 + slot * 8 + r8) * LDQ + scol,
                    Ks[bsel] + slot * 512);
        }
    };

    #pragma unroll
    for (int j = 0; j < 2; j++) {
        const int slot = w * 2 + j;
        gload16(Qg + (size_t)(slot * 8 + r8) * LDQ + scol, Qs + slot * 512);
    }
    VLOAD(0);
    KSTAGE(0, 0);
    asm volatile("s_waitcnt vmcnt(0)" ::: "memory");
    VWRITE(0);
    asm volatile("s_waitcnt lgkmcnt(0)" ::: "memory");
    __builtin_amdgcn_s_barrier();

    bfrag qf[2];
    #pragma unroll
    for (int kk = 0; kk < 2; kk++)
        qf[kk] = *reinterpret_cast<const bfrag*>(
            (const char*)Qs + SWZ(w * 16 + lr, kk * 64 + lg * 16));

    float m_run[4] = {-1e30f, -1e30f, -1e30f, -1e30f};
    float l_run[4] = {0.f, 0.f, 0.f, 0.f};
    f32x4 acc_o[4] = {};

    for (int kt = 0; kt <= qt; ++kt) {
        const int cur = kt & 1;
        if (kt < qt) {
            VLOAD(kt + 1);
            KSTAGE(kt + 1, cur ^ 1);
            asm volatile("s_waitcnt vmcnt(4)" ::: "memory");
        } else {
            asm volatile("s_waitcnt vmcnt(0)" ::: "memory");
        }
        __builtin_amdgcn_s_barrier();

        f32x4 s4[4] = {};
        #pragma unroll
        for (int kk = 0; kk < 2; kk++) {
            #pragma unroll
            for (int ni = 0; ni < 4; ni++) {
                const bfrag bk = *reinterpret_cast<const bfrag*>(
                    (const char*)Ks[cur] + SWZ(ni * 16 + lr, kk * 64 + lg * 16));
                s4[ni] = __builtin_amdgcn_mfma_f32_16x16x32_bf16(qf[kk], bk, s4[ni], 0, 0, 0);
            }
        }
        float p[4][4];
        #pragma unroll
        for (int ni = 0; ni < 4; ni++)
            #pragma unroll
            for (int rg = 0; rg < 4; rg++)
                p[ni][rg] = s4[ni][rg] * 0.125f;
        if (kt == qt) {
            #pragma unroll
            for (int ni = 0; ni < 4; ni++)
                #pragma unroll
                for (int rg = 0; rg < 4; rg++)
                    if (ni * 16 + lr > w * 16 + lg * 4 + rg) p[ni][rg] = -1e30f;
        }
        float sf[4];
        #pragma unroll
        for (int rg = 0; rg < 4; rg++) {
            float mx = fmaxf(fmaxf(p[0][rg], p[1][rg]), fmaxf(p[2][rg], p[3][rg]));
            #pragma unroll
            for (int o = 1; o < 16; o <<= 1) mx = fmaxf(mx, __shfl_xor(mx, o, 64));
            const float mn = fmaxf(m_run[rg], mx);
            sf[rg] = __expf(m_run[rg] - mn);
            m_run[rg] = mn;
        }
        float rsum[4] = {};
        #pragma unroll
        for (int ni = 0; ni < 4; ni++)
            #pragma unroll
            for (int rg = 0; rg < 4; rg++) {
                const float e = __expf(p[ni][rg] - m_run[rg]);
                p[ni][rg] = e;
                rsum[rg] += e;
            }
        #pragma unroll
        for (int rg = 0; rg < 4; rg++) {
            #pragma unroll
            for (int o = 1; o < 16; o <<= 1) rsum[rg] += __shfl_xor(rsum[rg], o, 64);
            l_run[rg] = l_run[rg] * sf[rg] + rsum[rg];
        }
        #pragma unroll
        for (int di = 0; di < 4; di++)
            #pragma unroll
            for (int rg = 0; rg < 4; rg++)
                acc_o[di][rg] *= sf[rg];

        if (kt < qt) VWRITE(cur ^ 1);

        unsigned short* pw = reinterpret_cast<unsigned short*>(Ps[w]);
        #pragma unroll
        for (int ni = 0; ni < 4; ni++)
            #pragma unroll
            for (int rg = 0; rg < 4; rg++) {
                const int prow = lg * 4 + rg;
                const int ad = SWZ(prow, (ni * 16 + lr) * 2);
                __hip_bfloat16 pb = __float2bfloat16(p[ni][rg]);
                pw[ad >> 1] = *reinterpret_cast<unsigned short*>(&pb);
            }
        #pragma unroll
        for (int kk = 0; kk < 2; kk++) {
            const bfrag pa = *reinterpret_cast<const bfrag*>(
                (const char*)Ps[w] + SWZ(lr, kk * 64 + lg * 16));
            #pragma unroll
            for (int di = 0; di < 4; di++) {
                const bfrag vb = *reinterpret_cast<const bfrag*>(
                    (const char*)Vts[cur] + SWZ(di * 16 + lr, kk * 64 + lg * 16));
                acc_o[di] = __builtin_amdgcn_mfma_f32_16x16x32_bf16(pa, vb, acc_o[di], 0, 0, 0);
            }
        }
        asm volatile("s_waitcnt lgkmcnt(0)" ::: "memory");
        __builtin_amdgcn_s_barrier();
    }
    #pragma unroll
    for (int di = 0; di < 4; di++)
        #pragma unroll
        for (int rg = 0; rg < 4; rg++) {
            const int q = qt * 64 + w * 16 + lg * 4 + rg;
            const float v = acc_o[di][rg] / l_run[rg];
            Oc[(size_t)(b * Ss + q) * Dm + h * 64 + di * 16 + lr] = __float2bfloat16(v);
        }
}

extern "C" void kernel_launch(void* const* d_in, const int* in_sizes, int n_in,
                              void* d_out, int out_size, void* d_ws, size_t ws_size,
                              hipStream_t stream) {
    const float* x   = (const float*)d_in[0];
    const float* Wq  = (const float*)d_in[1];
    const float* Wk  = (const float*)d_in[2];
    const float* Wv  = (const float*)d_in[3];
    const float* Wo  = (const float*)d_in[4];
    const float* bo  = (const float*)d_in[5];
    const float* g1  = (const float*)d_in[6];
    const float* be1 = (const float*)d_in[7];
    const float* g2  = (const float*)d_in[8];
    const float* be2 = (const float*)d_in[9];
    const float* W1  = (const float*)d_in[10];
    const float* b1  = (const float*)d_in[11];
    const float* W2  = (const float*)d_in[12];
    const float* b2  = (const float*)d_in[13];
    float* out = (float*)d_out;

    char* wsb = (char*)d_ws;
    __hip_bfloat16* WqkvT = (__hip_bfloat16*)(wsb);                 // [3072][1024]
    __hip_bfloat16* WoT   = (__hip_bfloat16*)(wsb + 6291456);       // [1024][1024]
    __hip_bfloat16* W1T   = (__hip_bfloat16*)(wsb + 8388608);       // [4096][1024]
    __hip_bfloat16* W2T   = (__hip_bfloat16*)(wsb + 16777216);      // [1024][4096]
    __hip_bfloat16* n1    = (__hip_bfloat16*)(wsb + 25165824);      // [8192][1024]
    __hip_bfloat16* QKV   = (__hip_bfloat16*)(wsb + 41943040);      // [8192][3072]
    __hip_bfloat16* concat = n1;
    __hip_bfloat16* n2     = n1;
    __hip_bfloat16* h1     = QKV;                                   // alias, [8192][4096]

    qkv_transpose_cvt<<<dim3(2, 32, 48), 256, 0, stream>>>(Wq, Wk, Wv, WqkvT);
    transpose_cvt<<<dim3(32, 32, 1), 256, 0, stream>>>(Wo, WoT, 1024, 1024, 0, 0);
    transpose_cvt<<<dim3(128, 32, 1), 256, 0, stream>>>(W1, W1T, 1024, 4096, 0, 0);
    transpose_cvt<<<dim3(32, 128, 1), 256, 0, stream>>>(W2, W2T, 4096, 1024, 0, 0);

    ln_bf16<<<NT, 256, 0, stream>>>(x, g1, be1, n1);
    // QKV: M=8192 N=3072 K=1024 -> 1536 blocks (nbx=24)
    gemm_db<0><<<1536, 256, 0, stream>>>(n1, Dm, WqkvT, Dm, nullptr, nullptr,
                                         QKV, 3072, 24, Dm);
    attn_mfma<<<NT * Hh / 64, 256, 0, stream>>>(QKV, concat);
    // proj: N=1024 -> 512 blocks (nbx=8)
    gemm_db<1><<<512, 256, 0, stream>>>(concat, Dm, WoT, Dm, bo, x,
                                        out, Dm, 8, Dm);
    ln_bf16<<<NT, 256, 0, stream>>>(out, g2, be2, n2);
    // FFN1: N=4096 -> 2048 blocks (nbx=32)
    gemm_db<2><<<2048, 256, 0, stream>>>(n2, Dm, W1T, Dm, b1, nullptr,
                                         h1, Ff, 32, Dm);
    // FFN2: M=8192 N=1024 K=4096 -> 512 blocks (nbx=8)
    gemm_db<3><<<512, 256, 0, stream>>>(h1, Ff, W2T, Ff, b2, nullptr,
                                        out, Dm, 8, Ff);
}

// Round 18
// 383.555 us; speedup vs baseline: 1.0537x; 1.0537x over previous
//
#include <hip/hip_runtime.h>
#include <hip/hip_bf16.h>
#include <math.h>

constexpr int Dm = 1024;
constexpr int Hh = 16;
constexpr int Ff = 4096;
constexpr int Ss = 512;
constexpr int Bbatch = 16;
constexpr int NT = Bbatch * Ss;   // 8192 tokens
constexpr float EPSc = 1e-5f;

typedef __attribute__((ext_vector_type(8))) short bfrag;   // 8 bf16 (4 VGPR)
typedef __attribute__((ext_vector_type(4))) float f32x4;

// tanh-form GELU, one v_exp, NaN-safe at +-inf of e (1 - 2/(e+1))
static __device__ __forceinline__ float gelu_f(float v) {
    const float u = v * (0.7978845608f + 0.0356774081f * v * v);
    const float e = __expf(2.0f * u);
    const float th = 1.0f - 2.0f / (e + 1.0f);
    return 0.5f * v * (1.0f + th);
}

static __device__ __forceinline__ void gload16(const void* g, void* l) {
    __builtin_amdgcn_global_load_lds((__attribute__((address_space(1))) void*)g,
                                     (__attribute__((address_space(3))) void*)l,
                                     16, 0, 0);
}

// XOR swizzle for [rows][128B-row] LDS tiles (G4): byte ^= ((row&7)<<4)
#define SWZ(row, colb) ((row) * 128 + ((colb) ^ (((row) & 7) << 4)))

// ---------------- transpose + fp32->bf16 convert: in [R][C] -> out [C][R] ---
__global__ void __launch_bounds__(256) transpose_cvt(const float* __restrict__ in,
                                                     __hip_bfloat16* __restrict__ out,
                                                     int R, int C,
                                                     long in_zs, long out_zs) {
    __shared__ float tile[32][33];
    const float* inz = in + (size_t)blockIdx.z * in_zs;
    __hip_bfloat16* outz = out + (size_t)blockIdx.z * out_zs;
    const int c0 = blockIdx.x * 32, r0 = blockIdx.y * 32;
    const int tx = threadIdx.x & 31, ty4 = (threadIdx.x >> 5) * 4;
    #pragma unroll
    for (int i = 0; i < 4; i++)
        tile[ty4 + i][tx] = inz[(size_t)(r0 + ty4 + i) * C + c0 + tx];
    __syncthreads();
    #pragma unroll
    for (int i = 0; i < 4; i++)
        outz[(size_t)(c0 + ty4 + i) * R + r0 + tx] = __float2bfloat16(tile[tx][ty4 + i]);
}

// merged Wq/Wk/Wv transpose: z in [0,48), matrix = z/16, per-head slice z%16
__global__ void __launch_bounds__(256) qkv_transpose_cvt(const float* __restrict__ Wq,
                                                         const float* __restrict__ Wk,
                                                         const float* __restrict__ Wv,
                                                         __hip_bfloat16* __restrict__ out) {
    __shared__ float tile[32][33];
    const int zm = blockIdx.z >> 4, zi = blockIdx.z & 15;
    const float* inz = (zm == 0 ? Wq : (zm == 1 ? Wk : Wv)) + (size_t)zi * 65536;
    __hip_bfloat16* outz = out + (size_t)zm * 1048576 + (size_t)zi * 65536;
    const int c0 = blockIdx.x * 32, r0 = blockIdx.y * 32;   // R=1024, C=64
    const int tx = threadIdx.x & 31, ty4 = (threadIdx.x >> 5) * 4;
    #pragma unroll
    for (int i = 0; i < 4; i++)
        tile[ty4 + i][tx] = inz[(size_t)(r0 + ty4 + i) * 64 + c0 + tx];
    __syncthreads();
    #pragma unroll
    for (int i = 0; i < 4; i++)
        outz[(size_t)(c0 + ty4 + i) * 1024 + r0 + tx] = __float2bfloat16(tile[tx][ty4 + i]);
}

// ---------------- LayerNorm fp32 in -> bf16 out ----------------------------
__global__ void __launch_bounds__(256) ln_bf16(const float* __restrict__ x,
                                               const float* __restrict__ gamma,
                                               const float* __restrict__ beta,
                                               __hip_bfloat16* __restrict__ out) {
    const int row = blockIdx.x;
    const int tid = threadIdx.x;
    const int lane = tid & 63, w = tid >> 6;
    float4 xv = reinterpret_cast<const float4*>(x + (size_t)row * Dm)[tid];
    float s  = xv.x + xv.y + xv.z + xv.w;
    float ss = xv.x * xv.x + xv.y * xv.y + xv.z * xv.z + xv.w * xv.w;
    #pragma unroll
    for (int o = 32; o > 0; o >>= 1) {
        s  += __shfl_down(s,  o, 64);
        ss += __shfl_down(ss, o, 64);
    }
    __shared__ float red[2][4];
    if (lane == 0) { red[0][w] = s; red[1][w] = ss; }
    __syncthreads();
    float st  = red[0][0] + red[0][1] + red[0][2] + red[0][3];
    float sst = red[1][0] + red[1][1] + red[1][2] + red[1][3];
    float mean = st * (1.0f / Dm);
    float var  = sst * (1.0f / Dm) - mean * mean;
    float inv  = rsqrtf(var + EPSc);
    float4 g = reinterpret_cast<const float4*>(gamma)[tid];
    float4 b = reinterpret_cast<const float4*>(beta)[tid];
    __hip_bfloat16 t[4] __attribute__((aligned(8)));
    t[0] = __float2bfloat16((xv.x - mean) * inv * g.x + b.x);
    t[1] = __float2bfloat16((xv.y - mean) * inv * g.y + b.y);
    t[2] = __float2bfloat16((xv.z - mean) * inv * g.z + b.z);
    t[3] = __float2bfloat16((xv.w - mean) * inv * g.w + b.w);
    *reinterpret_cast<ushort4*>(out + (size_t)row * Dm + tid * 4) =
        *reinterpret_cast<ushort4*>(t);
}

// ---------------- bf16 MFMA GEMM: dbuf + distance-2 + supertile (R13 best) -
// C = A[M,K] x Bt[N,K]^T. 128x128 tile, BK=64, 4 waves (2x2), 64 KiB dbuf.
// Per iter t: vmcnt(8) [STAGE(t) done, STAGE(t+1) in flight] -> barrier ->
// compute buf[t&1] -> barrier -> STAGE(t+2) into just-freed buffer.
// No sched_barrier/setprio (m141/m190); uniform SGPR bases + loop-invariant
// per-lane offsets for saddr-form staging. Both-sides XOR swizzle
// (conflict-free ds_read_b128). 8x8 super-tile order for per-XCD L2 fit.
// EPI 0: bf16 C                EPI 1: f32 C = acc + bias + res
// EPI 2: bf16 C = gelu(acc+b)  EPI 3: f32 C += acc + bias
template<int EPI>
__global__ void __launch_bounds__(256) gemm_db(const __hip_bfloat16* __restrict__ A, int lda,
                                               const __hip_bfloat16* __restrict__ Bt, int ldb,
                                               const float* __restrict__ bias,
                                               const float* __restrict__ res,
                                               void* __restrict__ Cout, int ldc,
                                               int nbx, int K) {
    __shared__ __hip_bfloat16 As[2][128 * 64];
    __shared__ __hip_bfloat16 Bs[2][128 * 64];
    const int tid = threadIdx.x, l = tid & 63, w = tid >> 6;
    const int lr = l & 15, lg = l >> 4;
    const int nwg = gridDim.x;
    const int sbid = (blockIdx.x & 7) * (nwg >> 3) + (blockIdx.x >> 3);
    // 8x8 super-tile mapping (per-XCD L2 working set ~4MB)
    const int st = sbid >> 6, wi = sbid & 63;
    const int nsx = nbx >> 3;
    const int bx = (st % nsx) * 8 + (wi & 7);
    const int by = (st / nsx) * 8 + (wi >> 3);
    const int m0 = by * 128, n0 = bx * 128;
    const int wr = w >> 1, wc = w & 1;
    const int srow = l >> 3;
    const int scol = ((l & 7) ^ srow) * 8;
    const int NK = K >> 6;

    // uniform bases (advance 64 elems/tile) + loop-invariant per-lane offsets
    const __hip_bfloat16* ubA = A  + (size_t)m0 * lda;
    const __hip_bfloat16* ubB = Bt + (size_t)n0 * ldb;
    int offA[4], offB[4];
    #pragma unroll
    for (int j = 0; j < 4; j++) {
        offA[j] = (w * 32 + j * 8 + srow) * lda + scol;
        offB[j] = (w * 32 + j * 8 + srow) * ldb + scol;
    }
    auto STAGE = [&](int bsel) {              // 8 gload16/thread, then advance
        #pragma unroll
        for (int j = 0; j < 4; j++) {
            const int rb = w * 32 + j * 8;
            gload16(ubA + offA[j], &As[bsel][rb * 64]);
            gload16(ubB + offB[j], &Bs[bsel][rb * 64]);
        }
        ubA += 64; ubB += 64;
    };

    f32x4 acc[4][4] = {};
    STAGE(0);
    STAGE(1);
    for (int t = 0; t < NK; t++) {
        const int cur = t & 1;
        if (t + 1 < NK) asm volatile("s_waitcnt vmcnt(8)" ::: "memory");
        else            asm volatile("s_waitcnt vmcnt(0)" ::: "memory");
        __builtin_amdgcn_s_barrier();
        const char* Ab = (const char*)&As[cur][0];
        const char* Bb = (const char*)&Bs[cur][0];
        #pragma unroll
        for (int kk = 0; kk < 2; kk++) {
            bfrag a[4], b[4];
            #pragma unroll
            for (int mi = 0; mi < 4; mi++) {
                const int row = wr * 64 + mi * 16 + lr;
                a[mi] = *(const bfrag*)(Ab + SWZ(row, (kk * 4 + lg) * 16));
            }
            #pragma unroll
            for (int ni = 0; ni < 4; ni++) {
                const int row = wc * 64 + ni * 16 + lr;
                b[ni] = *(const bfrag*)(Bb + SWZ(row, (kk * 4 + lg) * 16));
            }
            #pragma unroll
            for (int mi = 0; mi < 4; mi++)
                #pragma unroll
                for (int ni = 0; ni < 4; ni++)
                    acc[mi][ni] = __builtin_amdgcn_mfma_f32_16x16x32_bf16(a[mi], b[ni], acc[mi][ni], 0, 0, 0);
        }
        __builtin_amdgcn_s_barrier();         // all reads of buf[cur] done
        if (t + 2 < NK) STAGE(cur);           // tile t+2 -> just-freed buffer
    }
    const int rb = m0 + wr * 64 + lg * 4;
    const int cb = n0 + wc * 64 + lr;
    #pragma unroll
    for (int mi = 0; mi < 4; mi++) {
        #pragma unroll
        for (int ni = 0; ni < 4; ni++) {
            #pragma unroll
            for (int rg = 0; rg < 4; rg++) {
                const int row = rb + mi * 16 + rg;
                const int col = cb + ni * 16;
                const size_t off = (size_t)row * ldc + col;
                const float v = acc[mi][ni][rg];
                if (EPI == 0) {
                    ((__hip_bfloat16*)Cout)[off] = __float2bfloat16(v);
                } else if (EPI == 1) {
                    ((float*)Cout)[off] = v + bias[col] + res[off];
                } else if (EPI == 2) {
                    ((__hip_bfloat16*)Cout)[off] = __float2bfloat16(gelu_f(v + bias[col]));
                } else {
                    ((float*)Cout)[off] = ((float*)Cout)[off] + v + bias[col];
                }
            }
        }
    }
}

// ---------------- Flash attention: K/V double-buffered, counted vmcnt ------
// (R10-R16 proven kernel, unchanged.)
__global__ void __launch_bounds__(256) attn_mfma(const __hip_bfloat16* __restrict__ QKV,
                                                 __hip_bfloat16* __restrict__ Oc) {
    constexpr int LDQ = 3072;
    __shared__ __hip_bfloat16 Qs[64 * 64];
    __shared__ __hip_bfloat16 Ks[2][64 * 64];
    __shared__ __hip_bfloat16 Vts[2][64 * 64];   // V^T [feat][key]
    __shared__ __hip_bfloat16 Ps[4][16 * 64];    // per-wave P
    const int tid = threadIdx.x, l = tid & 63, w = tid >> 6;
    const int lr = l & 15, lg = l >> 4;
    const int qt = 7 - (blockIdx.x & 7);         // LPT: heavy tiles first
    const int h  = (blockIdx.x >> 3) & 15;
    const int b  = blockIdx.x >> 7;

    const __hip_bfloat16* Qg = QKV + (size_t)(b * Ss + qt * 64) * LDQ + h * 64;
    const __hip_bfloat16* Kg = QKV + (size_t)(b * Ss) * LDQ + 1024 + h * 64;
    const __hip_bfloat16* Vg = QKV + (size_t)(b * Ss) * LDQ + 2048 + h * 64;

    const int r8 = l >> 3;
    const int scol = 8 * ((l & 7) ^ r8);         // pre-swizzled source col

    const int vkey0 = tid >> 3, vf0 = (tid & 7) * 8;
    const int vkey1 = (tid + 256) >> 3, vf1 = vf0;

    uint4 vr[2];
    auto VLOAD = [&](int kt) {
        vr[0] = *reinterpret_cast<const uint4*>(Vg + (size_t)(kt * 64 + vkey0) * LDQ + vf0);
        vr[1] = *reinterpret_cast<const uint4*>(Vg + (size_t)(kt * 64 + vkey1) * LDQ + vf1);
    };
    auto VWRITE = [&](int bsel) {
        unsigned short* vt = reinterpret_cast<unsigned short*>(Vts[bsel]);
        #pragma unroll
        for (int j = 0; j < 2; j++) {
            const int key = j ? vkey1 : vkey0, f0 = j ? vf1 : vf0;
            const unsigned int rw[4] = {vr[j].x, vr[j].y, vr[j].z, vr[j].w};
            #pragma unroll
            for (int e2 = 0; e2 < 8; e2++) {
                const int feat = f0 + e2;
                const int ad = feat * 128 + ((key * 2) ^ ((feat & 7) << 4));
                vt[ad >> 1] = (unsigned short)(rw[e2 >> 1] >> ((e2 & 1) * 16));
            }
        }
    };
    auto KSTAGE = [&](int kt, int bsel) {
        #pragma unroll
        for (int j = 0; j < 2; j++) {
            const int slot = w * 2 + j;
            gload16(Kg + (size_t)(kt * 64 + slot * 8 + r8) * LDQ + scol,
                    Ks[bsel] + slot * 512);
        }
    };

    #pragma unroll
    for (int j = 0; j < 2; j++) {
        const int slot = w * 2 + j;
        gload16(Qg + (size_t)(slot * 8 + r8) * LDQ + scol, Qs + slot * 512);
    }
    VLOAD(0);
    KSTAGE(0, 0);
    asm volatile("s_waitcnt vmcnt(0)" ::: "memory");
    VWRITE(0);
    asm volatile("s_waitcnt lgkmcnt(0)" ::: "memory");
    __builtin_amdgcn_s_barrier();

    bfrag qf[2];
    #pragma unroll
    for (int kk = 0; kk < 2; kk++)
        qf[kk] = *reinterpret_cast<const bfrag*>(
            (const char*)Qs + SWZ(w * 16 + lr, kk * 64 + lg * 16));

    float m_run[4] = {-1e30f, -1e30f, -1e30f, -1e30f};
    float l_run[4] = {0.f, 0.f, 0.f, 0.f};
    f32x4 acc_o[4] = {};

    for (int kt = 0; kt <= qt; ++kt) {
        const int cur = kt & 1;
        if (kt < qt) {
            VLOAD(kt + 1);
            KSTAGE(kt + 1, cur ^ 1);
            asm volatile("s_waitcnt vmcnt(4)" ::: "memory");
        } else {
            asm volatile("s_waitcnt vmcnt(0)" ::: "memory");
        }
        __builtin_amdgcn_s_barrier();

        f32x4 s4[4] = {};
        #pragma unroll
        for (int kk = 0; kk < 2; kk++) {
            #pragma unroll
            for (int ni = 0; ni < 4; ni++) {
                const bfrag bk = *reinterpret_cast<const bfrag*>(
                    (const char*)Ks[cur] + SWZ(ni * 16 + lr, kk * 64 + lg * 16));
                s4[ni] = __builtin_amdgcn_mfma_f32_16x16x32_bf16(qf[kk], bk, s4[ni], 0, 0, 0);
            }
        }
        float p[4][4];
        #pragma unroll
        for (int ni = 0; ni < 4; ni++)
            #pragma unroll
            for (int rg = 0; rg < 4; rg++)
                p[ni][rg] = s4[ni][rg] * 0.125f;
        if (kt == qt) {
            #pragma unroll
            for (int ni = 0; ni < 4; ni++)
                #pragma unroll
                for (int rg = 0; rg < 4; rg++)
                    if (ni * 16 + lr > w * 16 + lg * 4 + rg) p[ni][rg] = -1e30f;
        }
        float sf[4];
        #pragma unroll
        for (int rg = 0; rg < 4; rg++) {
            float mx = fmaxf(fmaxf(p[0][rg], p[1][rg]), fmaxf(p[2][rg], p[3][rg]));
            #pragma unroll
            for (int o = 1; o < 16; o <<= 1) mx = fmaxf(mx, __shfl_xor(mx, o, 64));
            const float mn = fmaxf(m_run[rg], mx);
            sf[rg] = __expf(m_run[rg] - mn);
            m_run[rg] = mn;
        }
        float rsum[4] = {};
        #pragma unroll
        for (int ni = 0; ni < 4; ni++)
            #pragma unroll
            for (int rg = 0; rg < 4; rg++) {
                const float e = __expf(p[ni][rg] - m_run[rg]);
                p[ni][rg] = e;
                rsum[rg] += e;
            }
        #pragma unroll
        for (int rg = 0; rg < 4; rg++) {
            #pragma unroll
            for (int o = 1; o < 16; o <<= 1) rsum[rg] += __shfl_xor(rsum[rg], o, 64);
            l_run[rg] = l_run[rg] * sf[rg] + rsum[rg];
        }
        #pragma unroll
        for (int di = 0; di < 4; di++)
            #pragma unroll
            for (int rg = 0; rg < 4; rg++)
                acc_o[di][rg] *= sf[rg];

        if (kt < qt) VWRITE(cur ^ 1);

        unsigned short* pw = reinterpret_cast<unsigned short*>(Ps[w]);
        #pragma unroll
        for (int ni = 0; ni < 4; ni++)
            #pragma unroll
            for (int rg = 0; rg < 4; rg++) {
                const int prow = lg * 4 + rg;
                const int ad = SWZ(prow, (ni * 16 + lr) * 2);
                __hip_bfloat16 pb = __float2bfloat16(p[ni][rg]);
                pw[ad >> 1] = *reinterpret_cast<unsigned short*>(&pb);
            }
        #pragma unroll
        for (int kk = 0; kk < 2; kk++) {
            const bfrag pa = *reinterpret_cast<const bfrag*>(
                (const char*)Ps[w] + SWZ(lr, kk * 64 + lg * 16));
            #pragma unroll
            for (int di = 0; di < 4; di++) {
                const bfrag vb = *reinterpret_cast<const bfrag*>(
                    (const char*)Vts[cur] + SWZ(di * 16 + lr, kk * 64 + lg * 16));
                acc_o[di] = __builtin_amdgcn_mfma_f32_16x16x32_bf16(pa, vb, acc_o[di], 0, 0, 0);
            }
        }
        asm volatile("s_waitcnt lgkmcnt(0)" ::: "memory");
        __builtin_amdgcn_s_barrier();
    }
    #pragma unroll
    for (int di = 0; di < 4; di++)
        #pragma unroll
        for (int rg = 0; rg < 4; rg++) {
            const int q = qt * 64 + w * 16 + lg * 4 + rg;
            const float v = acc_o[di][rg] / l_run[rg];
            Oc[(size_t)(b * Ss + q) * Dm + h * 64 + di * 16 + lr] = __float2bfloat16(v);
        }
}

extern "C" void kernel_launch(void* const* d_in, const int* in_sizes, int n_in,
                              void* d_out, int out_size, void* d_ws, size_t ws_size,
                              hipStream_t stream) {
    const float* x   = (const float*)d_in[0];
    const float* Wq  = (const float*)d_in[1];
    const float* Wk  = (const float*)d_in[2];
    const float* Wv  = (const float*)d_in[3];
    const float* Wo  = (const float*)d_in[4];
    const float* bo  = (const float*)d_in[5];
    const float* g1  = (const float*)d_in[6];
    const float* be1 = (const float*)d_in[7];
    const float* g2  = (const float*)d_in[8];
    const float* be2 = (const float*)d_in[9];
    const float* W1  = (const float*)d_in[10];
    const float* b1  = (const float*)d_in[11];
    const float* W2  = (const float*)d_in[12];
    const float* b2  = (const float*)d_in[13];
    float* out = (float*)d_out;

    char* wsb = (char*)d_ws;
    __hip_bfloat16* WqkvT = (__hip_bfloat16*)(wsb);                 // [3072][1024]
    __hip_bfloat16* WoT   = (__hip_bfloat16*)(wsb + 6291456);       // [1024][1024]
    __hip_bfloat16* W1T   = (__hip_bfloat16*)(wsb + 8388608);       // [4096][1024]
    __hip_bfloat16* W2T   = (__hip_bfloat16*)(wsb + 16777216);      // [1024][4096]
    __hip_bfloat16* n1    = (__hip_bfloat16*)(wsb + 25165824);      // [8192][1024]
    __hip_bfloat16* QKV   = (__hip_bfloat16*)(wsb + 41943040);      // [8192][3072]
    __hip_bfloat16* concat = n1;
    __hip_bfloat16* n2     = n1;
    __hip_bfloat16* h1     = QKV;                                   // alias, [8192][4096]

    qkv_transpose_cvt<<<dim3(2, 32, 48), 256, 0, stream>>>(Wq, Wk, Wv, WqkvT);
    transpose_cvt<<<dim3(32, 32, 1), 256, 0, stream>>>(Wo, WoT, 1024, 1024, 0, 0);
    transpose_cvt<<<dim3(128, 32, 1), 256, 0, stream>>>(W1, W1T, 1024, 4096, 0, 0);
    transpose_cvt<<<dim3(32, 128, 1), 256, 0, stream>>>(W2, W2T, 4096, 1024, 0, 0);

    ln_bf16<<<NT, 256, 0, stream>>>(x, g1, be1, n1);
    // QKV: M=8192 N=3072 K=1024 -> 1536 blocks (nbx=24)
    gemm_db<0><<<1536, 256, 0, stream>>>(n1, Dm, WqkvT, Dm, nullptr, nullptr,
                                         QKV, 3072, 24, Dm);
    attn_mfma<<<NT * Hh / 64, 256, 0, stream>>>(QKV, concat);
    // proj: N=1024 -> 512 blocks (nbx=8)
    gemm_db<1><<<512, 256, 0, stream>>>(concat, Dm, WoT, Dm, bo, x,
                                        out, Dm, 8, Dm);
    ln_bf16<<<NT, 256, 0, stream>>>(out, g2, be2, n2);
    // FFN1: N=4096 -> 2048 blocks (nbx=32)
    gemm_db<2><<<2048, 256, 0, stream>>>(n2, Dm, W1T, Dm, b1, nullptr,
                                         h1, Ff, 32, Dm);
    // FFN2: M=8192 N=1024 K=4096 -> 512 blocks (nbx=8)
    gemm_db<3><<<512, 256, 0, stream>>>(h1, Ff, W2T, Ff, b2, nullptr,
                                        out, Dm, 8, Ff);
}